// Round 8
// baseline (272.485 us; speedup 1.0000x reference)
//
#include <hip/hip_runtime.h>

#define NCH 32
#define INCH 128
#define SH 7                  // nodes per coarse bucket = 128
#define BNODES 128
#define CAP 4544              // per-bucket capacity: avg 4092 + ~7 sigma
#define P1_CHUNK 4096
#define NBINS_PAD 1024        // coarse buckets padded for scan (N <= 131072)
#define HB 8                  // uints per half-row (16 bf16 channels)

typedef float  f4 __attribute__((ext_vector_type(4)));
typedef unsigned int u32;
typedef u32    uv4 __attribute__((ext_vector_type(4)));
typedef u32    uv2 __attribute__((ext_vector_type(2)));

// ---- bf16 pack/unpack (RNE) -------------------------------------------------
__device__ __forceinline__ u32 pack_bf16x2(float a, float b) {
  u32 ua = __float_as_uint(a);
  u32 ub = __float_as_uint(b);
  ua = (ua + 0x7FFFu + ((ua >> 16) & 1u)) >> 16;
  ub = (ub + 0x7FFFu + ((ub >> 16) & 1u)) & 0xFFFF0000u;
  return ub | ua;
}
__device__ __forceinline__ float lo_bf16(u32 u) { return __uint_as_float(u << 16); }
__device__ __forceinline__ float hi_bf16(u32 u) { return __uint_as_float(u & 0xFFFF0000u); }

// ---- init per-bucket write cursors ------------------------------------------
__global__ void k_initcur(int* gcur, int nbk) {
  int i = blockIdx.x * blockDim.x + threadIdx.x;
  if (i < nbk) gcur[i] = i * CAP;
}

// ---- P1: block-local counting sort into coarse buckets, chunked copy-out ----
__global__ __launch_bounds__(256) void k_part(const int* __restrict__ ei, int* gcur,
                                              u32* __restrict__ srcsb, int E) {
  __shared__ u32 sorted[P1_CHUNK];
  __shared__ unsigned short aux[P1_CHUNK];  // bucket id of each sorted slot
  __shared__ int hist[NBINS_PAD];           // counts, later global dest base
  __shared__ int bbase[NBINS_PAD + 1];
  __shared__ int bfill[NBINS_PAD];
  __shared__ int wsums[4];
  const int tid = threadIdx.x;
  const int base = blockIdx.x * P1_CHUNK;
  const int cnt = min(P1_CHUNK, E - base);

  for (int i = tid; i < NBINS_PAD; i += 256) hist[i] = 0;
  __syncthreads();
  for (int i = tid; i < cnt; i += 256) {
    int d = ei[E + base + i];
    atomicAdd(&hist[d >> SH], 1);
  }
  __syncthreads();
  int c0 = hist[4 * tid], c1 = hist[4 * tid + 1], c2 = hist[4 * tid + 2], c3 = hist[4 * tid + 3];
  int s = c0 + c1 + c2 + c3;
  int lane = tid & 63, w = tid >> 6;
  int incl = s;
#pragma unroll
  for (int off = 1; off < 64; off <<= 1) {
    int t = __shfl_up(incl, off, 64);
    if (lane >= off) incl += t;
  }
  if (lane == 63) wsums[w] = incl;
  __syncthreads();
  int woff = 0;
  for (int i = 0; i < w; ++i) woff += wsums[i];
  int te = woff + incl - s;
  bbase[4 * tid] = te;                     bfill[4 * tid] = te;
  bbase[4 * tid + 1] = te + c0;            bfill[4 * tid + 1] = te + c0;
  bbase[4 * tid + 2] = te + c0 + c1;       bfill[4 * tid + 2] = te + c0 + c1;
  bbase[4 * tid + 3] = te + c0 + c1 + c2;  bfill[4 * tid + 3] = te + c0 + c1 + c2;
  if (tid == 255) bbase[NBINS_PAD] = te + s;
  __syncthreads();
  for (int i = tid; i < cnt; i += 256) {
    int d = ei[E + base + i];
    int srcv = ei[base + i];
    int b = d >> SH;
    int pos = atomicAdd(&bfill[b], 1);
    sorted[pos] = ((u32)(d & (BNODES - 1)) << 17) | (u32)srcv;
    aux[pos] = (unsigned short)b;
  }
  __syncthreads();
  for (int b = tid; b < NBINS_PAD; b += 256) {
    int c = bbase[b + 1] - bbase[b];
    hist[b] = (c > 0) ? atomicAdd(&gcur[b], c) : 0;
  }
  __syncthreads();
  for (int i = tid; i < cnt; i += 256) {
    int b = aux[i];
    int gpos = hist[b] + (i - bbase[b]);
    if (gpos < (b + 1) * CAP) srcsb[gpos] = sorted[i];  // clamp vs overflow
  }
}

// ---- P2: per-bucket counting sort by node; emit rowbr/dis --------------------
__global__ __launch_bounds__(256) void k_bsort(const int* __restrict__ gcur,
                                               u32* __restrict__ srcsb,
                                               int2* __restrict__ rowbr,
                                               float* __restrict__ dis, int N) {
  __shared__ u32 raw[CAP];
  __shared__ u32 sbuf[CAP];
  __shared__ int hist2[BNODES];
  __shared__ int sc[BNODES];
  __shared__ int fill2[BNODES];
  const int tid = threadIdx.x;
  const int bin = blockIdx.x;
  const int base = bin * CAP;
  int cnt = min(gcur[bin] - base, CAP);

  if (tid < BNODES) hist2[tid] = 0;
  for (int i = tid; i < cnt; i += 256) raw[i] = srcsb[base + i];
  __syncthreads();
  for (int i = tid; i < cnt; i += 256) atomicAdd(&hist2[raw[i] >> 17], 1);
  __syncthreads();
  int deg = (tid < BNODES) ? hist2[tid] : 0;
  if (tid < BNODES) sc[tid] = deg;
  __syncthreads();
  for (int off = 1; off < BNODES; off <<= 1) {
    int t = 0;
    if (tid < BNODES && tid >= off) t = sc[tid - off];
    __syncthreads();
    if (tid < BNODES) sc[tid] += t;
    __syncthreads();
  }
  int excl = 0;
  if (tid < BNODES) { excl = sc[tid] - deg; fill2[tid] = excl; }
  __syncthreads();
  for (int i = tid; i < cnt; i += 256) {
    u32 v = raw[i];
    int pos = atomicAdd(&fill2[v >> 17], 1);
    sbuf[pos] = v & 0x1FFFFu;
  }
  __syncthreads();
  for (int i = tid; i < cnt; i += 256) srcsb[base + i] = sbuf[i];  // coalesced
  if (tid < BNODES) {
    int n = bin * BNODES + tid;
    if (n < N) {
      rowbr[n] = make_int2(base + excl, base + excl + deg);
      dis[n] = rsqrtf((float)(deg + 1));
    }
  }
}

// ---- layer 1 linear, register-tiled 8 nodes x 8 ch per thread ---------------
// Block = 64 threads (1 wave) = 16 node-groups x 4 ch-groups -> 128 nodes/block.
__global__ __launch_bounds__(64) void k_gemm1(const float* __restrict__ x,
                                              const float* __restrict__ W1,
                                              const float* __restrict__ dis,
                                              u32* __restrict__ hsA,
                                              u32* __restrict__ hsB, int N) {
  __shared__ f4 w4[INCH * 8];  // [k][8] float4s = [128][32] floats, 16 KB
  const int tid = threadIdx.x;
  {
    const f4* W14 = (const f4*)W1;
    for (int i = tid; i < INCH * 8; i += 64) w4[i] = W14[i];
  }
  __syncthreads();
  const int cg = tid & 3;         // channel group: ch cg*8 .. cg*8+7
  const int ng = tid >> 2;        // node group (0..15)
  const int nb = blockIdx.x * 128 + ng * 8;
  const f4* x4 = (const f4*)x;

  f4 acc0[8], acc1[8];
#pragma unroll
  for (int u = 0; u < 8; ++u) { acc0[u] = (f4)0.f; acc1[u] = (f4)0.f; }

  for (int kc = 0; kc < INCH; kc += 4) {
    f4 xv[8];
#pragma unroll
    for (int u = 0; u < 8; ++u) {
      int n = min(nb + u, N - 1);            // clamp; store is guarded
      xv[u] = x4[(size_t)n * 32 + (kc >> 2)];
    }
    f4 wA[4], wB[4];
#pragma unroll
    for (int j = 0; j < 4; ++j) {
      wA[j] = w4[(kc + j) * 8 + cg * 2];
      wB[j] = w4[(kc + j) * 8 + cg * 2 + 1];
    }
#pragma unroll
    for (int j = 0; j < 4; ++j) {
#pragma unroll
      for (int u = 0; u < 8; ++u) {
        acc0[u] += wA[j] * xv[u][j];
        acc1[u] += wB[j] * xv[u][j];
      }
    }
  }
#pragma unroll
  for (int u = 0; u < 8; ++u) {
    int n = nb + u;
    if (n >= N) break;
    float dn = dis[n];
    uv4 o;
    o.x = pack_bf16x2(acc0[u].x * dn, acc0[u].y * dn);
    o.y = pack_bf16x2(acc0[u].z * dn, acc0[u].w * dn);
    o.z = pack_bf16x2(acc1[u].x * dn, acc1[u].y * dn);
    o.w = pack_bf16x2(acc1[u].z * dn, acc1[u].w * dn);
    if (cg < 2) ((uv4*)hsA)[(size_t)n * 2 + cg] = o;
    else        ((uv4*)hsB)[(size_t)n * 2 + (cg - 2)] = o;
  }
}

// ---- half-table gather-aggregate: 4 lanes/node, uint2 rows ------------------
// Table (3.2 MB) stays cached; srcs stream + acc stream are nontemporal.
__global__ __launch_bounds__(256) void k_aggh(
    const int2* __restrict__ rowbr, const u32* __restrict__ srcs,
    const uv2* __restrict__ tbl2, f4* __restrict__ acc4, int N) {
  int n = blockIdx.x * 64 + (threadIdx.x >> 2);
  int c = threadIdx.x & 3;
  if (n >= N) return;
  int2 br = rowbr[n];
  int j = br.x, end = br.y;
  uv2 su = tbl2[(size_t)n * 4 + c];
  float a0 = lo_bf16(su.x), a1 = hi_bf16(su.x);
  float a2 = lo_bf16(su.y), a3 = hi_bf16(su.y);
  for (; j + 8 <= end; j += 8) {
    int s0 = __builtin_nontemporal_load(&srcs[j]);
    int s1 = __builtin_nontemporal_load(&srcs[j + 1]);
    int s2 = __builtin_nontemporal_load(&srcs[j + 2]);
    int s3 = __builtin_nontemporal_load(&srcs[j + 3]);
    int s4 = __builtin_nontemporal_load(&srcs[j + 4]);
    int s5 = __builtin_nontemporal_load(&srcs[j + 5]);
    int s6 = __builtin_nontemporal_load(&srcs[j + 6]);
    int s7 = __builtin_nontemporal_load(&srcs[j + 7]);
    uv2 u0 = tbl2[(size_t)s0 * 4 + c];
    uv2 u1 = tbl2[(size_t)s1 * 4 + c];
    uv2 u2 = tbl2[(size_t)s2 * 4 + c];
    uv2 u3 = tbl2[(size_t)s3 * 4 + c];
    uv2 u4 = tbl2[(size_t)s4 * 4 + c];
    uv2 u5 = tbl2[(size_t)s5 * 4 + c];
    uv2 u6 = tbl2[(size_t)s6 * 4 + c];
    uv2 u7 = tbl2[(size_t)s7 * 4 + c];
    a0 += ((lo_bf16(u0.x) + lo_bf16(u1.x)) + (lo_bf16(u2.x) + lo_bf16(u3.x))) +
          ((lo_bf16(u4.x) + lo_bf16(u5.x)) + (lo_bf16(u6.x) + lo_bf16(u7.x)));
    a1 += ((hi_bf16(u0.x) + hi_bf16(u1.x)) + (hi_bf16(u2.x) + hi_bf16(u3.x))) +
          ((hi_bf16(u4.x) + hi_bf16(u5.x)) + (hi_bf16(u6.x) + hi_bf16(u7.x)));
    a2 += ((lo_bf16(u0.y) + lo_bf16(u1.y)) + (lo_bf16(u2.y) + lo_bf16(u3.y))) +
          ((lo_bf16(u4.y) + lo_bf16(u5.y)) + (lo_bf16(u6.y) + lo_bf16(u7.y)));
    a3 += ((hi_bf16(u0.y) + hi_bf16(u1.y)) + (hi_bf16(u2.y) + hi_bf16(u3.y))) +
          ((hi_bf16(u4.y) + hi_bf16(u5.y)) + (hi_bf16(u6.y) + hi_bf16(u7.y)));
  }
  for (; j < end; ++j) {
    int s = __builtin_nontemporal_load(&srcs[j]);
    uv2 u = tbl2[(size_t)s * 4 + c];
    a0 += lo_bf16(u.x); a1 += hi_bf16(u.x);
    a2 += lo_bf16(u.y); a3 += hi_bf16(u.y);
  }
  f4 o;
  o.x = a0; o.y = a1; o.z = a2; o.w = a3;
  __builtin_nontemporal_store(o, &acc4[(size_t)n * 4 + c]);
}

// ---- mid MLP: t = relu(dis*acc + b1); hs2 = (t @ W2) * dis (split tables) ---
__global__ __launch_bounds__(256) void k_mlp2(
    const float2* __restrict__ accA, const float2* __restrict__ accB,
    const float* __restrict__ dis, const float* __restrict__ b1,
    const float* __restrict__ W2, u32* __restrict__ hs2A,
    u32* __restrict__ hs2B, int N) {
  __shared__ float w[NCH * NCH];
  for (int i = threadIdx.x; i < NCH * NCH; i += blockDim.x) w[i] = W2[i];
  __syncthreads();
  int n = blockIdx.x * 16 + (threadIdx.x >> 4);
  int c2 = threadIdx.x & 15;
  if (n >= N) return;
  float2 a = (c2 < 8) ? accA[(size_t)n * HB + c2] : accB[(size_t)n * HB + (c2 - 8)];
  float dn = dis[n];
  float v0 = fmaxf(fmaf(a.x, dn, b1[2 * c2]), 0.f);
  float v1 = fmaxf(fmaf(a.y, dn, b1[2 * c2 + 1]), 0.f);
  float o0 = 0.f, o1 = 0.f;
#pragma unroll
  for (int k2 = 0; k2 < 16; ++k2) {
    float va = __shfl(v0, k2, 16);
    float vb = __shfl(v1, k2, 16);
    float2 wa = ((const float2*)(w + (2 * k2) * NCH))[c2];
    float2 wb = ((const float2*)(w + (2 * k2 + 1) * NCH))[c2];
    o0 = fmaf(va, wa.x, fmaf(vb, wb.x, o0));
    o1 = fmaf(va, wa.y, fmaf(vb, wb.y, o1));
  }
  u32 p = pack_bf16x2(o0 * dn, o1 * dn);
  if (c2 < 8) hs2A[(size_t)n * HB + c2] = p;
  else        hs2B[(size_t)n * HB + (c2 - 8)] = p;
}

// ---- head: v = relu(dis*acc2 + b2); out[n] = v·Wc + bc ----------------------
__global__ __launch_bounds__(256) void k_head(
    const float2* __restrict__ accA, const float2* __restrict__ accB,
    const float* __restrict__ dis, const float* __restrict__ b2,
    const float* __restrict__ Wc, const float* __restrict__ bc,
    float* __restrict__ out, int N) {
  int n = blockIdx.x * 16 + (threadIdx.x >> 4);
  int c2 = threadIdx.x & 15;
  if (n >= N) return;
  float2 a = (c2 < 8) ? accA[(size_t)n * HB + c2] : accB[(size_t)n * HB + (c2 - 8)];
  float dn = dis[n];
  float v0 = fmaxf(fmaf(a.x, dn, b2[2 * c2]), 0.f);
  float v1 = fmaxf(fmaf(a.y, dn, b2[2 * c2 + 1]), 0.f);
  float s0 = v0 * Wc[(2 * c2) * 2 + 0] + v1 * Wc[(2 * c2 + 1) * 2 + 0];
  float s1 = v0 * Wc[(2 * c2) * 2 + 1] + v1 * Wc[(2 * c2 + 1) * 2 + 1];
#pragma unroll
  for (int off = 8; off > 0; off >>= 1) {
    s0 += __shfl_down(s0, off, 16);
    s1 += __shfl_down(s1, off, 16);
  }
  if (c2 == 0) {
    out[(size_t)n * 2 + 0] = s0 + bc[0];
    out[(size_t)n * 2 + 1] = s1 + bc[1];
  }
}

extern "C" void kernel_launch(void* const* d_in, const int* in_sizes, int n_in,
                              void* d_out, int out_size, void* d_ws, size_t ws_size,
                              hipStream_t stream) {
  const float* x  = (const float*)d_in[0];
  const int*   ei = (const int*)d_in[1];
  const float* W1 = (const float*)d_in[2];
  const float* b1 = (const float*)d_in[3];
  const float* W2 = (const float*)d_in[4];
  const float* b2 = (const float*)d_in[5];
  const float* Wc = (const float*)d_in[6];
  const float* bc = (const float*)d_in[7];
  float* out = (float*)d_out;

  const int N = in_sizes[0] / INCH;  // 100000
  const int E = in_sizes[1] / 2;     // 3200000
  const int nbk = (N + BNODES - 1) / BNODES;  // 782

  // workspace layout (4B elems; every section 16B-aligned)
  float* dis    = (float*)d_ws;                              // N
  int2*  rowbr  = (int2*)(dis + N);                          // N int2
  int*   gcur   = (int*)(rowbr + N);                         // nbk (pad 784)
  u32*   srcsb  = (u32*)(gcur + 784);                        // nbk*CAP
  u32*   hsA    = srcsb + (size_t)nbk * CAP;                 // N*8 (bf16x2, ch 0-15)
  u32*   hsB    = hsA + (size_t)N * HB;                      // N*8 (ch 16-31)
  float2* accA  = (float2*)(hsB + (size_t)N * HB);           // N*8 float2
  float2* accB  = accA + (size_t)N * HB;                     // N*8 float2
  u32*   hs2A   = (u32*)(accB + (size_t)N * HB);             // N*8
  u32*   hs2B   = hs2A + (size_t)N * HB;                     // N*8

  const int bn = 256;
  const int gP1   = (E + P1_CHUNK - 1) / P1_CHUNK;   // 782
  const int gN16  = (N + 15) / 16;                   // 6250
  const int gN64  = (N + 63) / 64;                   // 1563
  const int gN128 = (N + 127) / 128;                 // 782

  k_initcur<<<(nbk + bn - 1) / bn, bn, 0, stream>>>(gcur, nbk);
  k_part<<<gP1, bn, 0, stream>>>(ei, gcur, srcsb, E);
  k_bsort<<<nbk, bn, 0, stream>>>(gcur, srcsb, rowbr, dis, N);

  // layer 1
  k_gemm1<<<gN128, 64, 0, stream>>>(x, W1, dis, hsA, hsB, N);
  k_aggh<<<gN64, bn, 0, stream>>>(rowbr, srcsb, (const uv2*)hsA, (f4*)accA, N);
  k_aggh<<<gN64, bn, 0, stream>>>(rowbr, srcsb, (const uv2*)hsB, (f4*)accB, N);
  k_mlp2<<<gN16, bn, 0, stream>>>(accA, accB, dis, b1, W2, hs2A, hs2B, N);

  // layer 2 + head
  k_aggh<<<gN64, bn, 0, stream>>>(rowbr, srcsb, (const uv2*)hs2A, (f4*)accA, N);
  k_aggh<<<gN64, bn, 0, stream>>>(rowbr, srcsb, (const uv2*)hs2B, (f4*)accB, N);
  k_head<<<gN16, bn, 0, stream>>>(accA, accB, dis, b2, Wc, bc, out, N);
}

// Round 9
// 208.566 us; speedup vs baseline: 1.3065x; 1.3065x over previous
//
#include <hip/hip_runtime.h>

#define NCH 32
#define INCH 128
#define SH 7                  // nodes per coarse bucket = 128
#define BNODES 128
#define CAP 4544              // per-bucket capacity: avg 4092 + ~7 sigma
#define P1_CHUNK 4096
#define NBINS_PAD 1024        // coarse buckets padded for scan (N <= 131072)
#define HB 8                  // uints per half-row (16 bf16 channels)

typedef float  f4 __attribute__((ext_vector_type(4)));
typedef unsigned int u32;
typedef u32    uv4 __attribute__((ext_vector_type(4)));

// ---- bf16 pack/unpack (RNE) -------------------------------------------------
__device__ __forceinline__ u32 pack_bf16x2(float a, float b) {
  u32 ua = __float_as_uint(a);
  u32 ub = __float_as_uint(b);
  ua = (ua + 0x7FFFu + ((ua >> 16) & 1u)) >> 16;
  ub = (ub + 0x7FFFu + ((ub >> 16) & 1u)) & 0xFFFF0000u;
  return ub | ua;
}
__device__ __forceinline__ float lo_bf16(u32 u) { return __uint_as_float(u << 16); }
__device__ __forceinline__ float hi_bf16(u32 u) { return __uint_as_float(u & 0xFFFF0000u); }

// ---- init per-bucket write cursors ------------------------------------------
__global__ void k_initcur(int* gcur, int nbk) {
  int i = blockIdx.x * blockDim.x + threadIdx.x;
  if (i < nbk) gcur[i] = i * CAP;
}

// ---- P1: block-local counting sort into coarse buckets, chunked copy-out ----
__global__ __launch_bounds__(256) void k_part(const int* __restrict__ ei, int* gcur,
                                              u32* __restrict__ srcsb, int E) {
  __shared__ u32 sorted[P1_CHUNK];
  __shared__ unsigned short aux[P1_CHUNK];  // bucket id of each sorted slot
  __shared__ int hist[NBINS_PAD];           // counts, later global dest base
  __shared__ int bbase[NBINS_PAD + 1];
  __shared__ int bfill[NBINS_PAD];
  __shared__ int wsums[4];
  const int tid = threadIdx.x;
  const int base = blockIdx.x * P1_CHUNK;
  const int cnt = min(P1_CHUNK, E - base);

  for (int i = tid; i < NBINS_PAD; i += 256) hist[i] = 0;
  __syncthreads();
  for (int i = tid; i < cnt; i += 256) {
    int d = ei[E + base + i];
    atomicAdd(&hist[d >> SH], 1);
  }
  __syncthreads();
  int c0 = hist[4 * tid], c1 = hist[4 * tid + 1], c2 = hist[4 * tid + 2], c3 = hist[4 * tid + 3];
  int s = c0 + c1 + c2 + c3;
  int lane = tid & 63, w = tid >> 6;
  int incl = s;
#pragma unroll
  for (int off = 1; off < 64; off <<= 1) {
    int t = __shfl_up(incl, off, 64);
    if (lane >= off) incl += t;
  }
  if (lane == 63) wsums[w] = incl;
  __syncthreads();
  int woff = 0;
  for (int i = 0; i < w; ++i) woff += wsums[i];
  int te = woff + incl - s;
  bbase[4 * tid] = te;                     bfill[4 * tid] = te;
  bbase[4 * tid + 1] = te + c0;            bfill[4 * tid + 1] = te + c0;
  bbase[4 * tid + 2] = te + c0 + c1;       bfill[4 * tid + 2] = te + c0 + c1;
  bbase[4 * tid + 3] = te + c0 + c1 + c2;  bfill[4 * tid + 3] = te + c0 + c1 + c2;
  if (tid == 255) bbase[NBINS_PAD] = te + s;
  __syncthreads();
  for (int i = tid; i < cnt; i += 256) {
    int d = ei[E + base + i];
    int srcv = ei[base + i];
    int b = d >> SH;
    int pos = atomicAdd(&bfill[b], 1);
    sorted[pos] = ((u32)(d & (BNODES - 1)) << 17) | (u32)srcv;
    aux[pos] = (unsigned short)b;
  }
  __syncthreads();
  for (int b = tid; b < NBINS_PAD; b += 256) {
    int c = bbase[b + 1] - bbase[b];
    hist[b] = (c > 0) ? atomicAdd(&gcur[b], c) : 0;
  }
  __syncthreads();
  for (int i = tid; i < cnt; i += 256) {
    int b = aux[i];
    int gpos = hist[b] + (i - bbase[b]);
    if (gpos < (b + 1) * CAP) srcsb[gpos] = sorted[i];  // clamp vs overflow
  }
}

// ---- P2: per-bucket counting sort by node; emit rowbr/dis --------------------
__global__ __launch_bounds__(256) void k_bsort(const int* __restrict__ gcur,
                                               u32* __restrict__ srcsb,
                                               int2* __restrict__ rowbr,
                                               float* __restrict__ dis, int N) {
  __shared__ u32 raw[CAP];
  __shared__ u32 sbuf[CAP];
  __shared__ int hist2[BNODES];
  __shared__ int fill2[BNODES];
  __shared__ int wsums2[2];
  const int tid = threadIdx.x;
  const int bin = blockIdx.x;
  const int base = bin * CAP;
  int cnt = min(gcur[bin] - base, CAP);

  if (tid < BNODES) hist2[tid] = 0;
  for (int i = tid; i < cnt; i += 256) raw[i] = srcsb[base + i];
  __syncthreads();
  for (int i = tid; i < cnt; i += 256) atomicAdd(&hist2[raw[i] >> 17], 1);
  __syncthreads();
  // 2-barrier shuffle scan over 128 degrees (waves 0 and 1)
  int deg = (tid < BNODES) ? hist2[tid] : 0;
  int incl = deg;
  {
    int lane = tid & 63;
#pragma unroll
    for (int off = 1; off < 64; off <<= 1) {
      int t = __shfl_up(incl, off, 64);
      if (lane >= off) incl += t;
    }
    if (tid < BNODES && lane == 63) wsums2[tid >> 6] = incl;
  }
  __syncthreads();
  int excl = incl - deg + ((tid >= 64 && tid < BNODES) ? wsums2[0] : 0);
  if (tid < BNODES) fill2[tid] = excl;
  __syncthreads();
  for (int i = tid; i < cnt; i += 256) {
    u32 v = raw[i];
    int pos = atomicAdd(&fill2[v >> 17], 1);
    sbuf[pos] = v & 0x1FFFFu;
  }
  __syncthreads();
  for (int i = tid; i < cnt; i += 256) srcsb[base + i] = sbuf[i];  // coalesced
  if (tid < BNODES) {
    int n = bin * BNODES + tid;
    if (n < N) {
      rowbr[n] = make_int2(base + excl, base + excl + deg);
      dis[n] = rsqrtf((float)(deg + 1));
    }
  }
}

// ---- layer 1 linear, register-tiled 2 nodes x 8 ch per thread ---------------
// Block = 256 threads (4 waves) = 64 node-slots x 4 ch-groups -> 128 nodes/block.
// 782 blocks x 4 waves = 3128 waves (12/CU) -> latency hidden, unlike r8's 782.
__global__ __launch_bounds__(256) void k_gemm1(const float* __restrict__ x,
                                               const float* __restrict__ W1,
                                               const float* __restrict__ dis,
                                               u32* __restrict__ hsA,
                                               u32* __restrict__ hsB, int N) {
  __shared__ f4 w4[INCH * 8];  // [k][8] float4s = [128][32] floats, 16 KB
  const int tid = threadIdx.x;
  {
    const f4* W14 = (const f4*)W1;
    for (int i = tid; i < INCH * 8; i += 256) w4[i] = W14[i];
  }
  __syncthreads();
  const int cg = tid & 3;         // channel group: ch cg*8 .. cg*8+7
  const int slot = tid >> 2;      // node slot (0..63)
  const int nb = blockIdx.x * 128 + slot * 2;
  const int na = min(nb, N - 1);
  const int nb2 = min(nb + 1, N - 1);
  const f4* x4 = (const f4*)x;

  f4 acc0a = (f4)0.f, acc1a = (f4)0.f, acc0b = (f4)0.f, acc1b = (f4)0.f;

#pragma unroll 4
  for (int j = 0; j < 32; ++j) {   // j = float4 index along k (4 k per j)
    f4 xa = x4[(size_t)na * 32 + j];
    f4 xb = x4[(size_t)nb2 * 32 + j];
#pragma unroll
    for (int r = 0; r < 4; ++r) {
      f4 wA = w4[(4 * j + r) * 8 + cg * 2];
      f4 wB = w4[(4 * j + r) * 8 + cg * 2 + 1];
      acc0a += wA * xa[r];
      acc1a += wB * xa[r];
      acc0b += wA * xb[r];
      acc1b += wB * xb[r];
    }
  }
#pragma unroll
  for (int u = 0; u < 2; ++u) {
    int n = nb + u;
    if (n >= N) break;
    f4 a0 = u ? acc0b : acc0a;
    f4 a1 = u ? acc1b : acc1a;
    float dn = dis[n];
    uv4 o;
    o.x = pack_bf16x2(a0.x * dn, a0.y * dn);
    o.y = pack_bf16x2(a0.z * dn, a0.w * dn);
    o.z = pack_bf16x2(a1.x * dn, a1.y * dn);
    o.w = pack_bf16x2(a1.z * dn, a1.w * dn);
    if (cg < 2) ((uv4*)hsA)[(size_t)n * 2 + cg] = o;
    else        ((uv4*)hsB)[(size_t)n * 2 + (cg - 2)] = o;
  }
}

// ---- half-table gather-aggregate (r6-proven): 8 lanes/node, u32 rows --------
__global__ __launch_bounds__(256) void k_aggh(
    const int2* __restrict__ rowbr, const u32* __restrict__ srcs,
    const u32* __restrict__ tbl, float2* __restrict__ acc, int N) {
  int n = blockIdx.x * 32 + (threadIdx.x >> 3);
  int c = threadIdx.x & 7;
  if (n >= N) return;
  int2 br = rowbr[n];
  int j = br.x, end = br.y;
  u32 su = tbl[(size_t)n * HB + c];
  float ax = lo_bf16(su), ay = hi_bf16(su);  // self loop
  for (; j + 8 <= end; j += 8) {
    u32 u0 = tbl[(size_t)srcs[j] * HB + c];
    u32 u1 = tbl[(size_t)srcs[j + 1] * HB + c];
    u32 u2 = tbl[(size_t)srcs[j + 2] * HB + c];
    u32 u3 = tbl[(size_t)srcs[j + 3] * HB + c];
    u32 u4 = tbl[(size_t)srcs[j + 4] * HB + c];
    u32 u5 = tbl[(size_t)srcs[j + 5] * HB + c];
    u32 u6 = tbl[(size_t)srcs[j + 6] * HB + c];
    u32 u7 = tbl[(size_t)srcs[j + 7] * HB + c];
    ax += ((lo_bf16(u0) + lo_bf16(u1)) + (lo_bf16(u2) + lo_bf16(u3))) +
          ((lo_bf16(u4) + lo_bf16(u5)) + (lo_bf16(u6) + lo_bf16(u7)));
    ay += ((hi_bf16(u0) + hi_bf16(u1)) + (hi_bf16(u2) + hi_bf16(u3))) +
          ((hi_bf16(u4) + hi_bf16(u5)) + (hi_bf16(u6) + hi_bf16(u7)));
  }
  for (; j < end; ++j) {
    u32 u = tbl[(size_t)srcs[j] * HB + c];
    ax += lo_bf16(u);
    ay += hi_bf16(u);
  }
  acc[(size_t)n * HB + c] = make_float2(ax, ay);
}

// ---- mid MLP: t = relu(dis*acc + b1); hs2 = (t @ W2) * dis (split tables) ---
__global__ __launch_bounds__(256) void k_mlp2(
    const float2* __restrict__ accA, const float2* __restrict__ accB,
    const float* __restrict__ dis, const float* __restrict__ b1,
    const float* __restrict__ W2, u32* __restrict__ hs2A,
    u32* __restrict__ hs2B, int N) {
  __shared__ float w[NCH * NCH];
  for (int i = threadIdx.x; i < NCH * NCH; i += blockDim.x) w[i] = W2[i];
  __syncthreads();
  int n = blockIdx.x * 16 + (threadIdx.x >> 4);
  int c2 = threadIdx.x & 15;
  if (n >= N) return;
  float2 a = (c2 < 8) ? accA[(size_t)n * HB + c2] : accB[(size_t)n * HB + (c2 - 8)];
  float dn = dis[n];
  float v0 = fmaxf(fmaf(a.x, dn, b1[2 * c2]), 0.f);
  float v1 = fmaxf(fmaf(a.y, dn, b1[2 * c2 + 1]), 0.f);
  float o0 = 0.f, o1 = 0.f;
#pragma unroll
  for (int k2 = 0; k2 < 16; ++k2) {
    float va = __shfl(v0, k2, 16);
    float vb = __shfl(v1, k2, 16);
    float2 wa = ((const float2*)(w + (2 * k2) * NCH))[c2];
    float2 wb = ((const float2*)(w + (2 * k2 + 1) * NCH))[c2];
    o0 = fmaf(va, wa.x, fmaf(vb, wb.x, o0));
    o1 = fmaf(va, wa.y, fmaf(vb, wb.y, o1));
  }
  u32 p = pack_bf16x2(o0 * dn, o1 * dn);
  if (c2 < 8) hs2A[(size_t)n * HB + c2] = p;
  else        hs2B[(size_t)n * HB + (c2 - 8)] = p;
}

// ---- head: v = relu(dis*acc2 + b2); out[n] = v·Wc + bc ----------------------
__global__ __launch_bounds__(256) void k_head(
    const float2* __restrict__ accA, const float2* __restrict__ accB,
    const float* __restrict__ dis, const float* __restrict__ b2,
    const float* __restrict__ Wc, const float* __restrict__ bc,
    float* __restrict__ out, int N) {
  int n = blockIdx.x * 16 + (threadIdx.x >> 4);
  int c2 = threadIdx.x & 15;
  if (n >= N) return;
  float2 a = (c2 < 8) ? accA[(size_t)n * HB + c2] : accB[(size_t)n * HB + (c2 - 8)];
  float dn = dis[n];
  float v0 = fmaxf(fmaf(a.x, dn, b2[2 * c2]), 0.f);
  float v1 = fmaxf(fmaf(a.y, dn, b2[2 * c2 + 1]), 0.f);
  float s0 = v0 * Wc[(2 * c2) * 2 + 0] + v1 * Wc[(2 * c2 + 1) * 2 + 0];
  float s1 = v0 * Wc[(2 * c2) * 2 + 1] + v1 * Wc[(2 * c2 + 1) * 2 + 1];
#pragma unroll
  for (int off = 8; off > 0; off >>= 1) {
    s0 += __shfl_down(s0, off, 16);
    s1 += __shfl_down(s1, off, 16);
  }
  if (c2 == 0) {
    out[(size_t)n * 2 + 0] = s0 + bc[0];
    out[(size_t)n * 2 + 1] = s1 + bc[1];
  }
}

extern "C" void kernel_launch(void* const* d_in, const int* in_sizes, int n_in,
                              void* d_out, int out_size, void* d_ws, size_t ws_size,
                              hipStream_t stream) {
  const float* x  = (const float*)d_in[0];
  const int*   ei = (const int*)d_in[1];
  const float* W1 = (const float*)d_in[2];
  const float* b1 = (const float*)d_in[3];
  const float* W2 = (const float*)d_in[4];
  const float* b2 = (const float*)d_in[5];
  const float* Wc = (const float*)d_in[6];
  const float* bc = (const float*)d_in[7];
  float* out = (float*)d_out;

  const int N = in_sizes[0] / INCH;  // 100000
  const int E = in_sizes[1] / 2;     // 3200000
  const int nbk = (N + BNODES - 1) / BNODES;  // 782

  // workspace layout (4B elems; every section 16B-aligned)
  float* dis    = (float*)d_ws;                              // N
  int2*  rowbr  = (int2*)(dis + N);                          // N int2
  int*   gcur   = (int*)(rowbr + N);                         // nbk (pad 784)
  u32*   srcsb  = (u32*)(gcur + 784);                        // nbk*CAP
  u32*   hsA    = srcsb + (size_t)nbk * CAP;                 // N*8 (bf16x2, ch 0-15)
  u32*   hsB    = hsA + (size_t)N * HB;                      // N*8 (ch 16-31)
  float2* accA  = (float2*)(hsB + (size_t)N * HB);           // N*8 float2
  float2* accB  = accA + (size_t)N * HB;                     // N*8 float2
  u32*   hs2A   = (u32*)(accB + (size_t)N * HB);             // N*8
  u32*   hs2B   = hs2A + (size_t)N * HB;                     // N*8

  const int bn = 256;
  const int gP1   = (E + P1_CHUNK - 1) / P1_CHUNK;   // 782
  const int gN16  = (N + 15) / 16;                   // 6250
  const int gN32  = (N + 31) / 32;                   // 3125
  const int gN128 = (N + 127) / 128;                 // 782

  k_initcur<<<(nbk + bn - 1) / bn, bn, 0, stream>>>(gcur, nbk);
  k_part<<<gP1, bn, 0, stream>>>(ei, gcur, srcsb, E);
  k_bsort<<<nbk, bn, 0, stream>>>(gcur, srcsb, rowbr, dis, N);

  // layer 1
  k_gemm1<<<gN128, bn, 0, stream>>>(x, W1, dis, hsA, hsB, N);
  k_aggh<<<gN32, bn, 0, stream>>>(rowbr, srcsb, hsA, accA, N);
  k_aggh<<<gN32, bn, 0, stream>>>(rowbr, srcsb, hsB, accB, N);
  k_mlp2<<<gN16, bn, 0, stream>>>(accA, accB, dis, b1, W2, hs2A, hs2B, N);

  // layer 2 + head
  k_aggh<<<gN32, bn, 0, stream>>>(rowbr, srcsb, hs2A, accA, N);
  k_aggh<<<gN32, bn, 0, stream>>>(rowbr, srcsb, hs2B, accB, N);
  k_head<<<gN16, bn, 0, stream>>>(accA, accB, dis, b2, Wc, bc, out, N);
}

// Round 10
// 197.421 us; speedup vs baseline: 1.3802x; 1.0565x over previous
//
#include <hip/hip_runtime.h>

#define NCH 32
#define INCH 128
#define SH 7                  // nodes per coarse bucket = 128
#define BNODES 128
#define CAP 4544              // per-bucket capacity: avg 4092 + ~7 sigma
#define P1_CHUNK 3072
#define NBINS_PAD 1024        // coarse buckets padded for scan (N <= 131072)
#define HB 8                  // uints per half-row (16 bf16 channels)

typedef float  f4 __attribute__((ext_vector_type(4)));
typedef unsigned int u32;
typedef u32    uv4 __attribute__((ext_vector_type(4)));

// ---- bf16 pack/unpack (RNE) -------------------------------------------------
__device__ __forceinline__ u32 pack_bf16x2(float a, float b) {
  u32 ua = __float_as_uint(a);
  u32 ub = __float_as_uint(b);
  ua = (ua + 0x7FFFu + ((ua >> 16) & 1u)) >> 16;
  ub = (ub + 0x7FFFu + ((ub >> 16) & 1u)) & 0xFFFF0000u;
  return ub | ua;
}
__device__ __forceinline__ float lo_bf16(u32 u) { return __uint_as_float(u << 16); }
__device__ __forceinline__ float hi_bf16(u32 u) { return __uint_as_float(u & 0xFFFF0000u); }

// ---- init per-bucket write cursors ------------------------------------------
__global__ void k_initcur(int* gcur, int nbk) {
  int i = blockIdx.x * blockDim.x + threadIdx.x;
  if (i < nbk) gcur[i] = i * CAP;
}

// ---- P1: block-local counting sort into coarse buckets, chunked copy-out ----
__global__ __launch_bounds__(256) void k_part(const int* __restrict__ ei, int* gcur,
                                              u32* __restrict__ srcsb, int E) {
  __shared__ u32 sorted[P1_CHUNK];
  __shared__ unsigned short aux[P1_CHUNK];  // bucket id of each sorted slot
  __shared__ int hist[NBINS_PAD];           // counts, later global dest base
  __shared__ int bbase[NBINS_PAD + 1];
  __shared__ int bfill[NBINS_PAD];
  __shared__ int wsums[4];
  const int tid = threadIdx.x;
  const int base = blockIdx.x * P1_CHUNK;
  const int cnt = min(P1_CHUNK, E - base);

  for (int i = tid; i < NBINS_PAD; i += 256) hist[i] = 0;
  __syncthreads();
  for (int i = tid; i < cnt; i += 256) {
    int d = ei[E + base + i];
    atomicAdd(&hist[d >> SH], 1);
  }
  __syncthreads();
  int c0 = hist[4 * tid], c1 = hist[4 * tid + 1], c2 = hist[4 * tid + 2], c3 = hist[4 * tid + 3];
  int s = c0 + c1 + c2 + c3;
  int lane = tid & 63, w = tid >> 6;
  int incl = s;
#pragma unroll
  for (int off = 1; off < 64; off <<= 1) {
    int t = __shfl_up(incl, off, 64);
    if (lane >= off) incl += t;
  }
  if (lane == 63) wsums[w] = incl;
  __syncthreads();
  int woff = 0;
  for (int i = 0; i < w; ++i) woff += wsums[i];
  int te = woff + incl - s;
  bbase[4 * tid] = te;                     bfill[4 * tid] = te;
  bbase[4 * tid + 1] = te + c0;            bfill[4 * tid + 1] = te + c0;
  bbase[4 * tid + 2] = te + c0 + c1;       bfill[4 * tid + 2] = te + c0 + c1;
  bbase[4 * tid + 3] = te + c0 + c1 + c2;  bfill[4 * tid + 3] = te + c0 + c1 + c2;
  if (tid == 255) bbase[NBINS_PAD] = te + s;
  __syncthreads();
  for (int i = tid; i < cnt; i += 256) {
    int d = ei[E + base + i];
    int srcv = ei[base + i];
    int b = d >> SH;
    int pos = atomicAdd(&bfill[b], 1);
    sorted[pos] = ((u32)(d & (BNODES - 1)) << 17) | (u32)srcv;
    aux[pos] = (unsigned short)b;
  }
  __syncthreads();
  for (int b = tid; b < NBINS_PAD; b += 256) {
    int c = bbase[b + 1] - bbase[b];
    hist[b] = (c > 0) ? atomicAdd(&gcur[b], c) : 0;
  }
  __syncthreads();
  for (int i = tid; i < cnt; i += 256) {
    int b = aux[i];
    int gpos = hist[b] + (i - bbase[b]);
    if (gpos < (b + 1) * CAP) srcsb[gpos] = sorted[i];  // clamp vs overflow
  }
}

// ---- P2: per-bucket counting sort by node; emit rowbr/dis --------------------
__global__ __launch_bounds__(256) void k_bsort(const int* __restrict__ gcur,
                                               u32* __restrict__ srcsb,
                                               int2* __restrict__ rowbr,
                                               float* __restrict__ dis, int N) {
  __shared__ u32 raw[CAP];
  __shared__ u32 sbuf[CAP];
  __shared__ int hist2[BNODES];
  __shared__ int fill2[BNODES];
  __shared__ int wsums2[2];
  const int tid = threadIdx.x;
  const int bin = blockIdx.x;
  const int base = bin * CAP;
  int cnt = min(gcur[bin] - base, CAP);

  if (tid < BNODES) hist2[tid] = 0;
  for (int i = tid; i < cnt; i += 256) raw[i] = srcsb[base + i];
  __syncthreads();
  for (int i = tid; i < cnt; i += 256) atomicAdd(&hist2[raw[i] >> 17], 1);
  __syncthreads();
  int deg = (tid < BNODES) ? hist2[tid] : 0;
  int incl = deg;
  {
    int lane = tid & 63;
#pragma unroll
    for (int off = 1; off < 64; off <<= 1) {
      int t = __shfl_up(incl, off, 64);
      if (lane >= off) incl += t;
    }
    if (tid < BNODES && lane == 63) wsums2[tid >> 6] = incl;
  }
  __syncthreads();
  int excl = incl - deg + ((tid >= 64 && tid < BNODES) ? wsums2[0] : 0);
  if (tid < BNODES) fill2[tid] = excl;
  __syncthreads();
  for (int i = tid; i < cnt; i += 256) {
    u32 v = raw[i];
    int pos = atomicAdd(&fill2[v >> 17], 1);
    sbuf[pos] = v & 0x1FFFFu;
  }
  __syncthreads();
  for (int i = tid; i < cnt; i += 256) srcsb[base + i] = sbuf[i];  // coalesced
  if (tid < BNODES) {
    int n = bin * BNODES + tid;
    if (n < N) {
      rowbr[n] = make_int2(base + excl, base + excl + deg);
      dis[n] = rsqrtf((float)(deg + 1));
    }
  }
}

// ---- layer 1 linear, register-tiled 2 nodes x 8 ch per thread ---------------
__global__ __launch_bounds__(256) void k_gemm1(const float* __restrict__ x,
                                               const float* __restrict__ W1,
                                               const float* __restrict__ dis,
                                               u32* __restrict__ hsA,
                                               u32* __restrict__ hsB, int N) {
  __shared__ f4 w4[INCH * 8];  // [k][8] float4s = [128][32] floats, 16 KB
  const int tid = threadIdx.x;
  {
    const f4* W14 = (const f4*)W1;
    for (int i = tid; i < INCH * 8; i += 256) w4[i] = W14[i];
  }
  __syncthreads();
  const int cg = tid & 3;         // channel group: ch cg*8 .. cg*8+7
  const int slot = tid >> 2;      // node slot (0..63)
  const int nb = blockIdx.x * 128 + slot * 2;
  const int na = min(nb, N - 1);
  const int nb2 = min(nb + 1, N - 1);
  const f4* x4 = (const f4*)x;

  f4 acc0a = (f4)0.f, acc1a = (f4)0.f, acc0b = (f4)0.f, acc1b = (f4)0.f;

#pragma unroll 4
  for (int j = 0; j < 32; ++j) {   // j = float4 index along k (4 k per j)
    f4 xa = x4[(size_t)na * 32 + j];
    f4 xb = x4[(size_t)nb2 * 32 + j];
#pragma unroll
    for (int r = 0; r < 4; ++r) {
      f4 wA = w4[(4 * j + r) * 8 + cg * 2];
      f4 wB = w4[(4 * j + r) * 8 + cg * 2 + 1];
      acc0a += wA * xa[r];
      acc1a += wB * xa[r];
      acc0b += wA * xb[r];
      acc1b += wB * xb[r];
    }
  }
#pragma unroll
  for (int u = 0; u < 2; ++u) {
    int n = nb + u;
    if (n >= N) break;
    f4 a0 = u ? acc0b : acc0a;
    f4 a1 = u ? acc1b : acc1a;
    float dn = dis[n];
    uv4 o;
    o.x = pack_bf16x2(a0.x * dn, a0.y * dn);
    o.y = pack_bf16x2(a0.z * dn, a0.w * dn);
    o.z = pack_bf16x2(a1.x * dn, a1.y * dn);
    o.w = pack_bf16x2(a1.z * dn, a1.w * dn);
    if (cg < 2) ((uv4*)hsA)[(size_t)n * 2 + cg] = o;
    else        ((uv4*)hsB)[(size_t)n * 2 + (cg - 2)] = o;
  }
}

// ---- gather-agg core for one half-table (8 lanes/node) ----------------------
__device__ __forceinline__ void gather_half(const u32* __restrict__ srcs,
                                            const u32* __restrict__ tbl,
                                            int n, int c, int j, int end,
                                            float& ax, float& ay) {
  u32 su = tbl[(size_t)n * HB + c];
  ax = lo_bf16(su); ay = hi_bf16(su);  // self loop
  for (; j + 8 <= end; j += 8) {
    u32 u0 = tbl[(size_t)srcs[j] * HB + c];
    u32 u1 = tbl[(size_t)srcs[j + 1] * HB + c];
    u32 u2 = tbl[(size_t)srcs[j + 2] * HB + c];
    u32 u3 = tbl[(size_t)srcs[j + 3] * HB + c];
    u32 u4 = tbl[(size_t)srcs[j + 4] * HB + c];
    u32 u5 = tbl[(size_t)srcs[j + 5] * HB + c];
    u32 u6 = tbl[(size_t)srcs[j + 6] * HB + c];
    u32 u7 = tbl[(size_t)srcs[j + 7] * HB + c];
    ax += ((lo_bf16(u0) + lo_bf16(u1)) + (lo_bf16(u2) + lo_bf16(u3))) +
          ((lo_bf16(u4) + lo_bf16(u5)) + (lo_bf16(u6) + lo_bf16(u7)));
    ay += ((hi_bf16(u0) + hi_bf16(u1)) + (hi_bf16(u2) + hi_bf16(u3))) +
          ((hi_bf16(u4) + hi_bf16(u5)) + (hi_bf16(u6) + hi_bf16(u7)));
  }
  for (; j < end; ++j) {
    u32 u = tbl[(size_t)srcs[j] * HB + c];
    ax += lo_bf16(u);
    ay += hi_bf16(u);
  }
}

// ---- half-A gather-aggregate -> fp32 acc ------------------------------------
__global__ __launch_bounds__(256) void k_aggh(
    const int2* __restrict__ rowbr, const u32* __restrict__ srcs,
    const u32* __restrict__ tbl, float2* __restrict__ acc, int N) {
  int n = blockIdx.x * 32 + (threadIdx.x >> 3);
  int c = threadIdx.x & 7;
  if (n >= N) return;
  int2 br = rowbr[n];
  float ax, ay;
  gather_half(srcs, tbl, n, c, br.x, br.y, ax, ay);
  acc[(size_t)n * HB + c] = make_float2(ax, ay);
}

// ---- half-B gather-agg + full MLP (relu -> @W2 -> *dis) fused ---------------
__global__ __launch_bounds__(256) void k_agghB_mlp(
    const int2* __restrict__ rowbr, const u32* __restrict__ srcs,
    const u32* __restrict__ tblB, const float2* __restrict__ accA,
    const float* __restrict__ dis, const float* __restrict__ b1,
    const float* __restrict__ W2, u32* __restrict__ hs2A,
    u32* __restrict__ hs2B, int N) {
  __shared__ float w[NCH * NCH];       // 4 KB
  __shared__ float tl[32][NCH + 1];    // 32 nodes x 33 (padded) = 4.2 KB
  const int tid = threadIdx.x;
  for (int i = tid; i < NCH * NCH; i += 256) w[i] = W2[i];
  const int ln = tid >> 3;  // local node 0..31
  const int c  = tid & 7;
  const int n = blockIdx.x * 32 + ln;
  const bool valid = (n < N);
  float dn = 0.f;
  if (valid) {
    int2 br = rowbr[n];
    float ax, ay;
    gather_half(srcs, tblB, n, c, br.x, br.y, ax, ay);
    dn = dis[n];
    float2 aA = accA[(size_t)n * HB + c];
    tl[ln][2 * c]          = fmaxf(fmaf(aA.x, dn, b1[2 * c]), 0.f);
    tl[ln][2 * c + 1]      = fmaxf(fmaf(aA.y, dn, b1[2 * c + 1]), 0.f);
    tl[ln][16 + 2 * c]     = fmaxf(fmaf(ax, dn, b1[16 + 2 * c]), 0.f);
    tl[ln][16 + 2 * c + 1] = fmaxf(fmaf(ay, dn, b1[16 + 2 * c + 1]), 0.f);
  }
  __syncthreads();
  if (!valid) return;
  float o0 = 0.f, o1 = 0.f, o2 = 0.f, o3 = 0.f;
#pragma unroll
  for (int k = 0; k < NCH; ++k) {
    float t = tl[ln][k];
    o0 = fmaf(t, w[k * NCH + 2 * c], o0);
    o1 = fmaf(t, w[k * NCH + 2 * c + 1], o1);
    o2 = fmaf(t, w[k * NCH + 16 + 2 * c], o2);
    o3 = fmaf(t, w[k * NCH + 16 + 2 * c + 1], o3);
  }
  hs2A[(size_t)n * HB + c] = pack_bf16x2(o0 * dn, o1 * dn);
  hs2B[(size_t)n * HB + c] = pack_bf16x2(o2 * dn, o3 * dn);
}

// ---- half-B gather-agg + classifier head fused ------------------------------
__global__ __launch_bounds__(256) void k_agghB_head(
    const int2* __restrict__ rowbr, const u32* __restrict__ srcs,
    const u32* __restrict__ tblB, const float2* __restrict__ accA,
    const float* __restrict__ dis, const float* __restrict__ b2,
    const float* __restrict__ Wc, const float* __restrict__ bc,
    float* __restrict__ out, int N) {
  int n = blockIdx.x * 32 + (threadIdx.x >> 3);
  int c = threadIdx.x & 7;
  if (n >= N) return;
  int2 br = rowbr[n];
  float ax, ay;
  gather_half(srcs, tblB, n, c, br.x, br.y, ax, ay);
  float dn = dis[n];
  float2 aA = accA[(size_t)n * HB + c];
  float v0 = fmaxf(fmaf(aA.x, dn, b2[2 * c]), 0.f);
  float v1 = fmaxf(fmaf(aA.y, dn, b2[2 * c + 1]), 0.f);
  float v2 = fmaxf(fmaf(ax, dn, b2[16 + 2 * c]), 0.f);
  float v3 = fmaxf(fmaf(ay, dn, b2[16 + 2 * c + 1]), 0.f);
  float s0 = v0 * Wc[(2 * c) * 2]     + v1 * Wc[(2 * c + 1) * 2] +
             v2 * Wc[(16 + 2 * c) * 2] + v3 * Wc[(16 + 2 * c + 1) * 2];
  float s1 = v0 * Wc[(2 * c) * 2 + 1]     + v1 * Wc[(2 * c + 1) * 2 + 1] +
             v2 * Wc[(16 + 2 * c) * 2 + 1] + v3 * Wc[(16 + 2 * c + 1) * 2 + 1];
#pragma unroll
  for (int off = 4; off > 0; off >>= 1) {
    s0 += __shfl_down(s0, off, 8);
    s1 += __shfl_down(s1, off, 8);
  }
  if (c == 0) {
    out[(size_t)n * 2 + 0] = s0 + bc[0];
    out[(size_t)n * 2 + 1] = s1 + bc[1];
  }
}

extern "C" void kernel_launch(void* const* d_in, const int* in_sizes, int n_in,
                              void* d_out, int out_size, void* d_ws, size_t ws_size,
                              hipStream_t stream) {
  const float* x  = (const float*)d_in[0];
  const int*   ei = (const int*)d_in[1];
  const float* W1 = (const float*)d_in[2];
  const float* b1 = (const float*)d_in[3];
  const float* W2 = (const float*)d_in[4];
  const float* b2 = (const float*)d_in[5];
  const float* Wc = (const float*)d_in[6];
  const float* bc = (const float*)d_in[7];
  float* out = (float*)d_out;

  const int N = in_sizes[0] / INCH;  // 100000
  const int E = in_sizes[1] / 2;     // 3200000
  const int nbk = (N + BNODES - 1) / BNODES;  // 782

  // workspace layout (4B elems; every section 16B-aligned)
  float* dis    = (float*)d_ws;                              // N
  int2*  rowbr  = (int2*)(dis + N);                          // N int2
  int*   gcur   = (int*)(rowbr + N);                         // nbk (pad 784)
  u32*   srcsb  = (u32*)(gcur + 784);                        // nbk*CAP
  u32*   hsA    = srcsb + (size_t)nbk * CAP;                 // N*8 (bf16x2, ch 0-15)
  u32*   hsB    = hsA + (size_t)N * HB;                      // N*8 (ch 16-31)
  float2* accA  = (float2*)(hsB + (size_t)N * HB);           // N*8 float2
  u32*   hs2A   = (u32*)(accA + (size_t)N * HB);             // N*8
  u32*   hs2B   = hs2A + (size_t)N * HB;                     // N*8

  const int bn = 256;
  const int gP1   = (E + P1_CHUNK - 1) / P1_CHUNK;   // 1042
  const int gN32  = (N + 31) / 32;                   // 3125
  const int gN128 = (N + 127) / 128;                 // 782

  k_initcur<<<(nbk + bn - 1) / bn, bn, 0, stream>>>(gcur, nbk);
  k_part<<<gP1, bn, 0, stream>>>(ei, gcur, srcsb, E);
  k_bsort<<<nbk, bn, 0, stream>>>(gcur, srcsb, rowbr, dis, N);

  // layer 1
  k_gemm1<<<gN128, bn, 0, stream>>>(x, W1, dis, hsA, hsB, N);
  k_aggh<<<gN32, bn, 0, stream>>>(rowbr, srcsb, hsA, accA, N);
  k_agghB_mlp<<<gN32, bn, 0, stream>>>(rowbr, srcsb, hsB, accA, dis, b1, W2, hs2A, hs2B, N);

  // layer 2 + head
  k_aggh<<<gN32, bn, 0, stream>>>(rowbr, srcsb, hs2A, accA, N);
  k_agghB_head<<<gN32, bn, 0, stream>>>(rowbr, srcsb, hs2B, accA, dis, b2, Wc, bc, out, N);
}

// Round 11
// 194.510 us; speedup vs baseline: 1.4009x; 1.0150x over previous
//
#include <hip/hip_runtime.h>

#define NCH 32
#define INCH 128
#define SH 7                  // nodes per coarse bucket = 128
#define BNODES 128
#define CAP 4544              // per-bucket capacity: avg 4092 + ~7 sigma
#define P1_CHUNK 4096
#define NBINS_PAD 1024        // coarse buckets padded for scan (N <= 131072)
#define HB 8                  // uints per half-row (16 bf16 channels)

typedef float  f4 __attribute__((ext_vector_type(4)));
typedef unsigned int u32;
typedef u32    uv4 __attribute__((ext_vector_type(4)));

// ---- bf16 pack/unpack (RNE) -------------------------------------------------
__device__ __forceinline__ u32 pack_bf16x2(float a, float b) {
  u32 ua = __float_as_uint(a);
  u32 ub = __float_as_uint(b);
  ua = (ua + 0x7FFFu + ((ua >> 16) & 1u)) >> 16;
  ub = (ub + 0x7FFFu + ((ub >> 16) & 1u)) & 0xFFFF0000u;
  return ub | ua;
}
__device__ __forceinline__ float lo_bf16(u32 u) { return __uint_as_float(u << 16); }
__device__ __forceinline__ float hi_bf16(u32 u) { return __uint_as_float(u & 0xFFFF0000u); }

// ---- init per-bucket write cursors ------------------------------------------
__global__ void k_initcur(int* gcur, int nbk) {
  int i = blockIdx.x * blockDim.x + threadIdx.x;
  if (i < nbk) gcur[i] = i * CAP;
}

// ---- P1: block-local counting sort into coarse buckets, chunked copy-out ----
__global__ __launch_bounds__(256) void k_part(const int* __restrict__ ei, int* gcur,
                                              u32* __restrict__ srcsb, int E) {
  __shared__ u32 sorted[P1_CHUNK];
  __shared__ unsigned short aux[P1_CHUNK];  // bucket id of each sorted slot
  __shared__ int hist[NBINS_PAD];           // counts, later global dest base
  __shared__ int bbase[NBINS_PAD + 1];
  __shared__ int bfill[NBINS_PAD];
  __shared__ int wsums[4];
  const int tid = threadIdx.x;
  const int base = blockIdx.x * P1_CHUNK;
  const int cnt = min(P1_CHUNK, E - base);

  for (int i = tid; i < NBINS_PAD; i += 256) hist[i] = 0;
  __syncthreads();
  for (int i = tid; i < cnt; i += 256) {
    int d = ei[E + base + i];
    atomicAdd(&hist[d >> SH], 1);
  }
  __syncthreads();
  int c0 = hist[4 * tid], c1 = hist[4 * tid + 1], c2 = hist[4 * tid + 2], c3 = hist[4 * tid + 3];
  int s = c0 + c1 + c2 + c3;
  int lane = tid & 63, w = tid >> 6;
  int incl = s;
#pragma unroll
  for (int off = 1; off < 64; off <<= 1) {
    int t = __shfl_up(incl, off, 64);
    if (lane >= off) incl += t;
  }
  if (lane == 63) wsums[w] = incl;
  __syncthreads();
  int woff = 0;
  for (int i = 0; i < w; ++i) woff += wsums[i];
  int te = woff + incl - s;
  bbase[4 * tid] = te;                     bfill[4 * tid] = te;
  bbase[4 * tid + 1] = te + c0;            bfill[4 * tid + 1] = te + c0;
  bbase[4 * tid + 2] = te + c0 + c1;       bfill[4 * tid + 2] = te + c0 + c1;
  bbase[4 * tid + 3] = te + c0 + c1 + c2;  bfill[4 * tid + 3] = te + c0 + c1 + c2;
  if (tid == 255) bbase[NBINS_PAD] = te + s;
  __syncthreads();
  for (int i = tid; i < cnt; i += 256) {
    int d = ei[E + base + i];
    int srcv = ei[base + i];
    int b = d >> SH;
    int pos = atomicAdd(&bfill[b], 1);
    sorted[pos] = ((u32)(d & (BNODES - 1)) << 17) | (u32)srcv;
    aux[pos] = (unsigned short)b;
  }
  __syncthreads();
  for (int b = tid; b < NBINS_PAD; b += 256) {
    int c = bbase[b + 1] - bbase[b];
    hist[b] = (c > 0) ? atomicAdd(&gcur[b], c) : 0;
  }
  __syncthreads();
  for (int i = tid; i < cnt; i += 256) {
    int b = aux[i];
    int gpos = hist[b] + (i - bbase[b]);
    if (gpos < (b + 1) * CAP) srcsb[gpos] = sorted[i];  // clamp vs overflow
  }
}

// ---- P2: per-bucket counting sort by node; emit rowbr/dis --------------------
__global__ __launch_bounds__(256) void k_bsort(const int* __restrict__ gcur,
                                               u32* __restrict__ srcsb,
                                               int2* __restrict__ rowbr,
                                               float* __restrict__ dis, int N) {
  __shared__ u32 raw[CAP];
  __shared__ u32 sbuf[CAP];
  __shared__ int hist2[BNODES];
  __shared__ int fill2[BNODES];
  __shared__ int wsums2[2];
  const int tid = threadIdx.x;
  const int bin = blockIdx.x;
  const int base = bin * CAP;
  int cnt = min(gcur[bin] - base, CAP);

  if (tid < BNODES) hist2[tid] = 0;
  for (int i = tid; i < cnt; i += 256) raw[i] = srcsb[base + i];
  __syncthreads();
  for (int i = tid; i < cnt; i += 256) atomicAdd(&hist2[raw[i] >> 17], 1);
  __syncthreads();
  int deg = (tid < BNODES) ? hist2[tid] : 0;
  int incl = deg;
  {
    int lane = tid & 63;
#pragma unroll
    for (int off = 1; off < 64; off <<= 1) {
      int t = __shfl_up(incl, off, 64);
      if (lane >= off) incl += t;
    }
    if (tid < BNODES && lane == 63) wsums2[tid >> 6] = incl;
  }
  __syncthreads();
  int excl = incl - deg + ((tid >= 64 && tid < BNODES) ? wsums2[0] : 0);
  if (tid < BNODES) fill2[tid] = excl;
  __syncthreads();
  for (int i = tid; i < cnt; i += 256) {
    u32 v = raw[i];
    int pos = atomicAdd(&fill2[v >> 17], 1);
    sbuf[pos] = v & 0x1FFFFu;
  }
  __syncthreads();
  for (int i = tid; i < cnt; i += 256) srcsb[base + i] = sbuf[i];  // coalesced
  if (tid < BNODES) {
    int n = bin * BNODES + tid;
    if (n < N) {
      rowbr[n] = make_int2(base + excl, base + excl + deg);
      dis[n] = rsqrtf((float)(deg + 1));
    }
  }
}

// ---- layer 1 linear, register-tiled 2 nodes x 8 ch per thread ---------------
__global__ __launch_bounds__(256) void k_gemm1(const float* __restrict__ x,
                                               const float* __restrict__ W1,
                                               const float* __restrict__ dis,
                                               u32* __restrict__ hsA,
                                               u32* __restrict__ hsB, int N) {
  __shared__ f4 w4[INCH * 8];  // [k][8] float4s = [128][32] floats, 16 KB
  const int tid = threadIdx.x;
  {
    const f4* W14 = (const f4*)W1;
    for (int i = tid; i < INCH * 8; i += 256) w4[i] = W14[i];
  }
  __syncthreads();
  const int cg = tid & 3;         // channel group: ch cg*8 .. cg*8+7
  const int slot = tid >> 2;      // node slot (0..63)
  const int nb = blockIdx.x * 128 + slot * 2;
  const int na = min(nb, N - 1);
  const int nb2 = min(nb + 1, N - 1);
  const f4* x4 = (const f4*)x;

  f4 acc0a = (f4)0.f, acc1a = (f4)0.f, acc0b = (f4)0.f, acc1b = (f4)0.f;

#pragma unroll 4
  for (int j = 0; j < 32; ++j) {   // j = float4 index along k (4 k per j)
    f4 xa = x4[(size_t)na * 32 + j];
    f4 xb = x4[(size_t)nb2 * 32 + j];
#pragma unroll
    for (int r = 0; r < 4; ++r) {
      f4 wA = w4[(4 * j + r) * 8 + cg * 2];
      f4 wB = w4[(4 * j + r) * 8 + cg * 2 + 1];
      acc0a += wA * xa[r];
      acc1a += wB * xa[r];
      acc0b += wA * xb[r];
      acc1b += wB * xb[r];
    }
  }
#pragma unroll
  for (int u = 0; u < 2; ++u) {
    int n = nb + u;
    if (n >= N) break;
    f4 a0 = u ? acc0b : acc0a;
    f4 a1 = u ? acc1b : acc1a;
    float dn = dis[n];
    uv4 o;
    o.x = pack_bf16x2(a0.x * dn, a0.y * dn);
    o.y = pack_bf16x2(a0.z * dn, a0.w * dn);
    o.z = pack_bf16x2(a1.x * dn, a1.y * dn);
    o.w = pack_bf16x2(a1.z * dn, a1.w * dn);
    if (cg < 2) ((uv4*)hsA)[(size_t)n * 2 + cg] = o;
    else        ((uv4*)hsB)[(size_t)n * 2 + (cg - 2)] = o;
  }
}

// ---- gather-agg core for one half-table (8 lanes/node) ----------------------
__device__ __forceinline__ void gather_half(const u32* __restrict__ srcs,
                                            const u32* __restrict__ tbl,
                                            int n, int c, int j, int end,
                                            float& ax, float& ay) {
  u32 su = tbl[(size_t)n * HB + c];
  ax = lo_bf16(su); ay = hi_bf16(su);  // self loop
  for (; j + 8 <= end; j += 8) {
    u32 u0 = tbl[(size_t)srcs[j] * HB + c];
    u32 u1 = tbl[(size_t)srcs[j + 1] * HB + c];
    u32 u2 = tbl[(size_t)srcs[j + 2] * HB + c];
    u32 u3 = tbl[(size_t)srcs[j + 3] * HB + c];
    u32 u4 = tbl[(size_t)srcs[j + 4] * HB + c];
    u32 u5 = tbl[(size_t)srcs[j + 5] * HB + c];
    u32 u6 = tbl[(size_t)srcs[j + 6] * HB + c];
    u32 u7 = tbl[(size_t)srcs[j + 7] * HB + c];
    ax += ((lo_bf16(u0) + lo_bf16(u1)) + (lo_bf16(u2) + lo_bf16(u3))) +
          ((lo_bf16(u4) + lo_bf16(u5)) + (lo_bf16(u6) + lo_bf16(u7)));
    ay += ((hi_bf16(u0) + hi_bf16(u1)) + (hi_bf16(u2) + hi_bf16(u3))) +
          ((hi_bf16(u4) + hi_bf16(u5)) + (hi_bf16(u6) + hi_bf16(u7)));
  }
  for (; j < end; ++j) {
    u32 u = tbl[(size_t)srcs[j] * HB + c];
    ax += lo_bf16(u);
    ay += hi_bf16(u);
  }
}

// ---- combined half-A/half-B gather-aggregate, XCD-parity split --------------
// blockIdx&1 selects the half; consecutive blocks round-robin XCDs, so each
// XCD's private L2 caches only its 3.2 MB sub-table. Perf heuristic only.
__global__ __launch_bounds__(256) void k_aggx(
    const int2* __restrict__ rowbr, const u32* __restrict__ srcs,
    const u32* __restrict__ tblA, const u32* __restrict__ tblB,
    float2* __restrict__ accA, float2* __restrict__ accB, int N) {
  const int half = blockIdx.x & 1;
  int n = (blockIdx.x >> 1) * 32 + (threadIdx.x >> 3);
  int c = threadIdx.x & 7;
  if (n >= N) return;
  const u32* tbl = half ? tblB : tblA;
  float2* acc = half ? accB : accA;
  int2 br = rowbr[n];
  float ax, ay;
  gather_half(srcs, tbl, n, c, br.x, br.y, ax, ay);
  acc[(size_t)n * HB + c] = make_float2(ax, ay);
}

// ---- mid MLP: t = relu(dis*acc + b1); hs2 = (t @ W2) * dis (split tables) ---
__global__ __launch_bounds__(256) void k_mlp2(
    const float2* __restrict__ accA, const float2* __restrict__ accB,
    const float* __restrict__ dis, const float* __restrict__ b1,
    const float* __restrict__ W2, u32* __restrict__ hs2A,
    u32* __restrict__ hs2B, int N) {
  __shared__ float w[NCH * NCH];
  for (int i = threadIdx.x; i < NCH * NCH; i += blockDim.x) w[i] = W2[i];
  __syncthreads();
  int n = blockIdx.x * 16 + (threadIdx.x >> 4);
  int c2 = threadIdx.x & 15;
  if (n >= N) return;
  float2 a = (c2 < 8) ? accA[(size_t)n * HB + c2] : accB[(size_t)n * HB + (c2 - 8)];
  float dn = dis[n];
  float v0 = fmaxf(fmaf(a.x, dn, b1[2 * c2]), 0.f);
  float v1 = fmaxf(fmaf(a.y, dn, b1[2 * c2 + 1]), 0.f);
  float o0 = 0.f, o1 = 0.f;
#pragma unroll
  for (int k2 = 0; k2 < 16; ++k2) {
    float va = __shfl(v0, k2, 16);
    float vb = __shfl(v1, k2, 16);
    float2 wa = ((const float2*)(w + (2 * k2) * NCH))[c2];
    float2 wb = ((const float2*)(w + (2 * k2 + 1) * NCH))[c2];
    o0 = fmaf(va, wa.x, fmaf(vb, wb.x, o0));
    o1 = fmaf(va, wa.y, fmaf(vb, wb.y, o1));
  }
  u32 p = pack_bf16x2(o0 * dn, o1 * dn);
  if (c2 < 8) hs2A[(size_t)n * HB + c2] = p;
  else        hs2B[(size_t)n * HB + (c2 - 8)] = p;
}

// ---- head: v = relu(dis*acc2 + b2); out[n] = v·Wc + bc ----------------------
__global__ __launch_bounds__(256) void k_head(
    const float2* __restrict__ accA, const float2* __restrict__ accB,
    const float* __restrict__ dis, const float* __restrict__ b2,
    const float* __restrict__ Wc, const float* __restrict__ bc,
    float* __restrict__ out, int N) {
  int n = blockIdx.x * 16 + (threadIdx.x >> 4);
  int c2 = threadIdx.x & 15;
  if (n >= N) return;
  float2 a = (c2 < 8) ? accA[(size_t)n * HB + c2] : accB[(size_t)n * HB + (c2 - 8)];
  float dn = dis[n];
  float v0 = fmaxf(fmaf(a.x, dn, b2[2 * c2]), 0.f);
  float v1 = fmaxf(fmaf(a.y, dn, b2[2 * c2 + 1]), 0.f);
  float s0 = v0 * Wc[(2 * c2) * 2 + 0] + v1 * Wc[(2 * c2 + 1) * 2 + 0];
  float s1 = v0 * Wc[(2 * c2) * 2 + 1] + v1 * Wc[(2 * c2 + 1) * 2 + 1];
#pragma unroll
  for (int off = 8; off > 0; off >>= 1) {
    s0 += __shfl_down(s0, off, 16);
    s1 += __shfl_down(s1, off, 16);
  }
  if (c2 == 0) {
    out[(size_t)n * 2 + 0] = s0 + bc[0];
    out[(size_t)n * 2 + 1] = s1 + bc[1];
  }
}

extern "C" void kernel_launch(void* const* d_in, const int* in_sizes, int n_in,
                              void* d_out, int out_size, void* d_ws, size_t ws_size,
                              hipStream_t stream) {
  const float* x  = (const float*)d_in[0];
  const int*   ei = (const int*)d_in[1];
  const float* W1 = (const float*)d_in[2];
  const float* b1 = (const float*)d_in[3];
  const float* W2 = (const float*)d_in[4];
  const float* b2 = (const float*)d_in[5];
  const float* Wc = (const float*)d_in[6];
  const float* bc = (const float*)d_in[7];
  float* out = (float*)d_out;

  const int N = in_sizes[0] / INCH;  // 100000
  const int E = in_sizes[1] / 2;     // 3200000
  const int nbk = (N + BNODES - 1) / BNODES;  // 782

  // workspace layout (4B elems; every section 16B-aligned)
  float* dis    = (float*)d_ws;                              // N
  int2*  rowbr  = (int2*)(dis + N);                          // N int2
  int*   gcur   = (int*)(rowbr + N);                         // nbk (pad 784)
  u32*   srcsb  = (u32*)(gcur + 784);                        // nbk*CAP
  u32*   hsA    = srcsb + (size_t)nbk * CAP;                 // N*8 (bf16x2, ch 0-15)
  u32*   hsB    = hsA + (size_t)N * HB;                      // N*8 (ch 16-31)
  float2* accA  = (float2*)(hsB + (size_t)N * HB);           // N*8 float2
  float2* accB  = accA + (size_t)N * HB;                     // N*8 float2
  u32*   hs2A   = (u32*)(accB + (size_t)N * HB);             // N*8
  u32*   hs2B   = hs2A + (size_t)N * HB;                     // N*8

  const int bn = 256;
  const int gP1   = (E + P1_CHUNK - 1) / P1_CHUNK;   // 782
  const int gN16  = (N + 15) / 16;                   // 6250
  const int gN32  = (N + 31) / 32;                   // 3125
  const int gN128 = (N + 127) / 128;                 // 782

  k_initcur<<<(nbk + bn - 1) / bn, bn, 0, stream>>>(gcur, nbk);
  k_part<<<gP1, bn, 0, stream>>>(ei, gcur, srcsb, E);
  k_bsort<<<nbk, bn, 0, stream>>>(gcur, srcsb, rowbr, dis, N);

  // layer 1: linear -> combined XCD-split aggregation -> MLP epilogue
  k_gemm1<<<gN128, bn, 0, stream>>>(x, W1, dis, hsA, hsB, N);
  k_aggx<<<2 * gN32, bn, 0, stream>>>(rowbr, srcsb, hsA, hsB, accA, accB, N);
  k_mlp2<<<gN16, bn, 0, stream>>>(accA, accB, dis, b1, W2, hs2A, hs2B, N);

  // layer 2: combined aggregation -> classifier head
  k_aggx<<<2 * gN32, bn, 0, stream>>>(rowbr, srcsb, hs2A, hs2B, accA, accB, N);
  k_head<<<gN16, bn, 0, stream>>>(accA, accB, dis, b2, Wc, bc, out, N);
}